// Round 1
// baseline (396.291 us; speedup 1.0000x reference)
//
#include <hip/hip_runtime.h>

typedef __attribute__((ext_vector_type(8))) short bf8_t;   // 8 bf16 (4 VGPRs)
typedef __attribute__((ext_vector_type(4))) short s4_t;    // 4 bf16
typedef __attribute__((ext_vector_type(4))) float f4_t;    // 4 f32

#define DEV static __device__ __forceinline__

DEV short f2bf(float f) {
  union { float f; unsigned u; } x; x.f = f;
  unsigned r = x.u + 0x7FFFu + ((x.u >> 16) & 1u);   // RNE
  return (short)(r >> 16);
}
DEV float bf2f(short h) {
  union { unsigned u; float f; } x; x.u = ((unsigned)(unsigned short)h) << 16;
  return x.f;
}
DEV f4_t mfma16(bf8_t a, bf8_t b, f4_t c) {
  return __builtin_amdgcn_mfma_f32_16x16x32_bf16(a, b, c, 0, 0, 0);
}
DEV f4_t zf4() { f4_t v = {0.f, 0.f, 0.f, 0.f}; return v; }

// split f32x8 -> bf16 hi + bf16 lo
DEV void cvt8(const f4_t& f0, const f4_t& f1, bf8_t& hv, bf8_t& lv) {
#pragma unroll
  for (int i = 0; i < 4; i++) {
    short h = f2bf(f0[i]); hv[i] = h; lv[i] = f2bf(f0[i] - bf2f(h));
  }
#pragma unroll
  for (int i = 0; i < 4; i++) {
    short h = f2bf(f1[i]); hv[4 + i] = h; lv[4 + i] = f2bf(f1[i] - bf2f(h));
  }
}

// ---------------------------------------------------------------------------
// Kernel 1: fused QKV projection (split-bf16 MFMA GEMM) + RoPE epilogue
//   blocks [0,256): Q = x@wq (N=4096), rope + 1/sqrt(HD) -> qh/ql
//   blocks [256,320): K = k@wk (N=1024), rope -> kh/kl
//   blocks [320,384): V = v@wv (N=1024) -> vb
// Tile 64x64, BK=32, 4 waves (each 16x64).
// ---------------------------------------------------------------------------
__global__ __launch_bounds__(256)
void qkv_kernel(const float* __restrict__ x, const float* __restrict__ kin,
                const float* __restrict__ vin, const float* __restrict__ wq,
                const float* __restrict__ wk, const float* __restrict__ wv,
                const float* __restrict__ fcos, const float* __restrict__ fsin,
                short* __restrict__ qh, short* __restrict__ ql,
                short* __restrict__ kh, short* __restrict__ kl,
                short* __restrict__ vb)
{
  __shared__ short Ah[64][40], Al[64][40];   // [row][k]
  __shared__ short Bh[64][40], Bl[64][40];   // [n][k]  (w^T tile)

  int bid = blockIdx.x;
  int mode, lin, nblk, N;
  const float* A; const float* W;
  if (bid < 256)      { mode = 0; lin = bid;       nblk = 256; A = x;   W = wq; N = 4096; }
  else if (bid < 320) { mode = 1; lin = bid - 256; nblk = 64;  A = kin; W = wk; N = 1024; }
  else                { mode = 2; lin = bid - 320; nblk = 64;  A = vin; W = wv; N = 1024; }
  int chunk = nblk >> 3;                       // per-XCD contiguous chunk
  lin = (lin & 7) * chunk + (lin >> 3);
  int m0 = (lin & 3) * 64;
  int n0 = (lin >> 2) * 64;

  int tid = threadIdx.x, w = tid >> 6, l = tid & 63;
  f4_t acc[4];
#pragma unroll
  for (int i = 0; i < 4; i++) acc[i] = zf4();

  int arow = tid >> 2, akc = (tid & 3) * 8;    // A staging: row, k-chunk
  int bn = tid & 63,  bk = (tid >> 6) * 8;     // B staging: col n, k-chunk

  for (int kk = 0; kk < 4096; kk += 32) {
    __syncthreads();
    {   // stage A (f32 -> hi/lo bf16)
      const float* src = A + (m0 + arow) * 4096 + kk + akc;
      f4_t f0 = *(const f4_t*)src;
      f4_t f1 = *(const f4_t*)(src + 4);
      bf8_t hv, lv; cvt8(f0, f1, hv, lv);
      *(bf8_t*)&Ah[arow][akc] = hv;
      *(bf8_t*)&Al[arow][akc] = lv;
    }
    {   // stage B^T (column-gather; coalesced across lanes per k-row)
      f4_t f0, f1;
#pragma unroll
      for (int j = 0; j < 4; j++) f0[j] = W[(kk + bk + j) * N + n0 + bn];
#pragma unroll
      for (int j = 0; j < 4; j++) f1[j] = W[(kk + bk + 4 + j) * N + n0 + bn];
      bf8_t hv, lv; cvt8(f0, f1, hv, lv);
      *(bf8_t*)&Bh[bn][bk] = hv;
      *(bf8_t*)&Bl[bn][bk] = lv;
    }
    __syncthreads();
    bf8_t ah = *(const bf8_t*)&Ah[w * 16 + (l & 15)][(l >> 4) * 8];
    bf8_t al = *(const bf8_t*)&Al[w * 16 + (l & 15)][(l >> 4) * 8];
#pragma unroll
    for (int nt = 0; nt < 4; ++nt) {
      bf8_t bh = *(const bf8_t*)&Bh[nt * 16 + (l & 15)][(l >> 4) * 8];
      bf8_t bl = *(const bf8_t*)&Bl[nt * 16 + (l & 15)][(l >> 4) * 8];
      acc[nt] = mfma16(ah, bh, acc[nt]);
      acc[nt] = mfma16(ah, bl, acc[nt]);
      acc[nt] = mfma16(al, bh, acc[nt]);
    }
  }

  // epilogue: C row = (l>>4)*4+i (+ wave offset), col = nt*16 + (l&15)
  int cl = l & 15, gq = l >> 4;
#pragma unroll
  for (int nt = 0; nt < 4; ++nt) {
    int col = n0 + nt * 16 + cl;
#pragma unroll
    for (int i = 0; i < 4; i++) {
      int mrow = m0 + w * 16 + gq * 4 + i;
      int s = mrow & 15, bb = mrow >> 4;
      float val = acc[nt][i];
      if (mode == 2) {
        int idx = ((bb * 8 + (col >> 7)) * 16 + s) * 128 + (col & 127);
        vb[idx] = f2bf(val);
      } else {
        float other = __shfl_xor(val, 1);   // rope partner (col^1)
        int d = col & 127;
        int ifr = d >> 1;
        float c = fcos[s * 64 + ifr], sn = fsin[s * 64 + ifr];
        float r = ((col & 1) == 0) ? (val * c - other * sn)
                                   : (other * sn + val * c);
        if (mode == 0) {
          r *= 0.08838834764831845f;        // 1/sqrt(128)
          short hi_ = f2bf(r), lo_ = f2bf(r - bf2f(hi_));
          int h = col >> 7;
          int idx = ((bb * 8 + (h >> 2)) * 64 + (h & 3) * 16 + s) * 128 + d;
          qh[idx] = hi_; ql[idx] = lo_;
        } else {
          short hi_ = f2bf(r), lo_ = f2bf(r - bf2f(hi_));
          int idx = ((bb * 8 + (col >> 7)) * 16 + s) * 128 + d;
          kh[idx] = hi_; kl[idx] = lo_;
        }
      }
    }
  }
}

// ---------------------------------------------------------------------------
// Kernel 2: flash attention. Block = (bg, split). 4 waves; wave w owns q-rows
// r=w (16 rows = one rep). Q in regs (hi/lo), K hi/lo + V^T + P in LDS.
// ---------------------------------------------------------------------------
__global__ __launch_bounds__(256)
void attn_kernel(const float* __restrict__ ck, const float* __restrict__ cv,
                 const short* __restrict__ qhp, const short* __restrict__ qlp,
                 const short* __restrict__ khp, const short* __restrict__ klp,
                 const short* __restrict__ vbp, const int* __restrict__ startp,
                 float* __restrict__ Op, float* __restrict__ mp,
                 float* __restrict__ lp)
{
  __shared__ short Kh[64][136], Kl[64][136];  // [t][d]
  __shared__ short Vt[128][72];               // [d][t]
  __shared__ short Ps[4][16][72];             // per-wave P [qrow][t]

  int bid = blockIdx.x;
  int bg = bid >> 2, sp = bid & 3;
  int b = bg >> 3, g = bg & 7;
  int tid = threadIdx.x, w = tid >> 6, l = tid & 63;
  int start = *startp;

  bf8_t qfh[4], qfl[4];
  {
    int qoff = (bg * 64 + w * 16 + (l & 15)) * 128 + (l >> 4) * 8;
#pragma unroll
    for (int kt = 0; kt < 4; ++kt) {
      qfh[kt] = *(const bf8_t*)(qhp + qoff + kt * 32);
      qfl[kt] = *(const bf8_t*)(qlp + qoff + kt * 32);
    }
  }
  f4_t of[8];
#pragma unroll
  for (int i = 0; i < 8; i++) of[i] = zf4();
  float mrun[4], lrun[4];
#pragma unroll
  for (int i = 0; i < 4; i++) { mrun[i] = -1e30f; lrun[i] = 0.f; }

  int srow = tid >> 2, sdc = (tid & 3) * 32;   // staging: row, d-quarter

  for (int tile = 0; tile < 16; ++tile) {
    int tb = sp * 1024 + tile * 64;
    __syncthreads();
    {   // stage K (hi/lo)
      int t = tb + srow;
      if (t >= start) {
        const short* sh = khp + ((bg * 16) + (t - start)) * 128 + sdc;
        const short* sl = klp + ((bg * 16) + (t - start)) * 128 + sdc;
#pragma unroll
        for (int j = 0; j < 4; j++) {
          *(bf8_t*)&Kh[srow][sdc + j * 8] = *(const bf8_t*)(sh + j * 8);
          *(bf8_t*)&Kl[srow][sdc + j * 8] = *(const bf8_t*)(sl + j * 8);
        }
      } else {
        const float* src = ck + ((b * 4096 + t) * 8 + g) * 128 + sdc;
#pragma unroll
        for (int j = 0; j < 4; j++) {
          f4_t f0 = *(const f4_t*)(src + j * 8);
          f4_t f1 = *(const f4_t*)(src + j * 8 + 4);
          bf8_t hv, lv; cvt8(f0, f1, hv, lv);
          *(bf8_t*)&Kh[srow][sdc + j * 8] = hv;
          *(bf8_t*)&Kl[srow][sdc + j * 8] = lv;
        }
      }
    }
    {   // stage V transposed
      int t = tb + srow;
      if (t >= start) {
        const short* sv = vbp + ((bg * 16) + (t - start)) * 128 + sdc;
#pragma unroll
        for (int j = 0; j < 4; j++) {
          bf8_t vv = *(const bf8_t*)(sv + j * 8);
#pragma unroll
          for (int i = 0; i < 8; i++) Vt[sdc + j * 8 + i][srow] = vv[i];
        }
      } else {
        const float* src = cv + ((b * 4096 + t) * 8 + g) * 128 + sdc;
#pragma unroll
        for (int j = 0; j < 8; j++) {
          f4_t f = *(const f4_t*)(src + j * 4);
#pragma unroll
          for (int i = 0; i < 4; i++) Vt[sdc + j * 4 + i][srow] = f2bf(f[i]);
        }
      }
    }
    __syncthreads();

    // QK^T (split: qh*kh + qh*kl + ql*kh)
    f4_t sf[4];
#pragma unroll
    for (int i = 0; i < 4; i++) sf[i] = zf4();
#pragma unroll
    for (int tt = 0; tt < 4; ++tt) {
#pragma unroll
      for (int kt = 0; kt < 4; ++kt) {
        bf8_t kbh = *(const bf8_t*)&Kh[tt * 16 + (l & 15)][kt * 32 + (l >> 4) * 8];
        bf8_t kbl = *(const bf8_t*)&Kl[tt * 16 + (l & 15)][kt * 32 + (l >> 4) * 8];
        sf[tt] = mfma16(qfh[kt], kbh, sf[tt]);
        sf[tt] = mfma16(qfh[kt], kbl, sf[tt]);
        sf[tt] = mfma16(qfl[kt], kbh, sf[tt]);
      }
    }

    // online softmax; C layout: row=(l>>4)*4+i, col=tt*16+(l&15)
    float mt[4];
#pragma unroll
    for (int i = 0; i < 4; i++)
      mt[i] = fmaxf(fmaxf(sf[0][i], sf[1][i]), fmaxf(sf[2][i], sf[3][i]));
#pragma unroll
    for (int st = 1; st < 16; st <<= 1)
#pragma unroll
      for (int i = 0; i < 4; i++) mt[i] = fmaxf(mt[i], __shfl_xor(mt[i], st));
    float sc[4];
#pragma unroll
    for (int i = 0; i < 4; i++) {
      float mn = fmaxf(mrun[i], mt[i]);
      sc[i] = __expf(mrun[i] - mn);
      mrun[i] = mn;
    }
    float rs[4] = {0.f, 0.f, 0.f, 0.f};
#pragma unroll
    for (int tt = 0; tt < 4; ++tt)
#pragma unroll
      for (int i = 0; i < 4; i++) {
        float pexp = __expf(sf[tt][i] - mrun[i]);
        rs[i] += pexp;
        Ps[w][(l >> 4) * 4 + i][tt * 16 + (l & 15)] = f2bf(pexp);
      }
#pragma unroll
    for (int st = 1; st < 16; st <<= 1)
#pragma unroll
      for (int i = 0; i < 4; i++) rs[i] += __shfl_xor(rs[i], st);
#pragma unroll
    for (int i = 0; i < 4; i++) lrun[i] = lrun[i] * sc[i] + rs[i];
#pragma unroll
    for (int dt = 0; dt < 8; ++dt)
#pragma unroll
      for (int i = 0; i < 4; i++) of[dt][i] *= sc[i];

    // PV
#pragma unroll
    for (int kt2 = 0; kt2 < 2; ++kt2) {
      bf8_t pa = *(const bf8_t*)&Ps[w][l & 15][kt2 * 32 + (l >> 4) * 8];
#pragma unroll
      for (int dt = 0; dt < 8; ++dt) {
        bf8_t vf = *(const bf8_t*)&Vt[dt * 16 + (l & 15)][kt2 * 32 + (l >> 4) * 8];
        of[dt] = mfma16(pa, vf, of[dt]);
      }
    }
  }

  // write partials
  int obase = ((bg * 4 + sp) * 64 + w * 16) * 128;
#pragma unroll
  for (int dt = 0; dt < 8; ++dt)
#pragma unroll
    for (int i = 0; i < 4; i++)
      Op[obase + ((l >> 4) * 4 + i) * 128 + dt * 16 + (l & 15)] = of[dt][i];
  if ((l & 15) == 0) {
    int rbase = (bg * 4 + sp) * 64 + w * 16 + (l >> 4) * 4;
#pragma unroll
    for (int i = 0; i < 4; i++) { mp[rbase + i] = mrun[i]; lp[rbase + i] = lrun[i]; }
  }
}

// ---------------------------------------------------------------------------
// Kernel 3: merge the 4 softmax partials -> bf16 attn-out (256 x 4096)
// ---------------------------------------------------------------------------
__global__ __launch_bounds__(256)
void merge_kernel(const float* __restrict__ Op, const float* __restrict__ mp,
                  const float* __restrict__ lp, short* __restrict__ attnb)
{
  int bg = blockIdx.x;
  int tid = threadIdx.x;
  int row = tid >> 2, dc = (tid & 3) * 32;
  int b = bg >> 3, g = bg & 7;
  int r = row >> 4, s = row & 15;
  float mm[4], ww[4];
  float M = -1e30f;
#pragma unroll
  for (int spp = 0; spp < 4; ++spp) {
    mm[spp] = mp[(bg * 4 + spp) * 64 + row];
    M = fmaxf(M, mm[spp]);
  }
  float denom = 0.f;
#pragma unroll
  for (int spp = 0; spp < 4; ++spp) {
    ww[spp] = __expf(mm[spp] - M);
    denom += lp[(bg * 4 + spp) * 64 + row] * ww[spp];
  }
  float inv = 1.0f / denom;
  int ob = (b * 16 + s) * 4096 + (g * 4 + r) * 128 + dc;
#pragma unroll
  for (int j = 0; j < 8; j++) {
    f4_t a = zf4();
#pragma unroll
    for (int spp = 0; spp < 4; ++spp) {
      f4_t o = *(const f4_t*)(Op + ((bg * 4 + spp) * 64 + row) * 128 + dc + j * 4);
#pragma unroll
      for (int i = 0; i < 4; i++) a[i] += ww[spp] * o[i];
    }
    s4_t o4;
#pragma unroll
    for (int i = 0; i < 4; i++) o4[i] = f2bf(a[i] * inv);
    *(s4_t*)(attnb + ob + j * 4) = o4;
  }
}

// ---------------------------------------------------------------------------
// Kernel 4: output projection  attn(bf16, 256x4096) @ wo(4096x4096) -> f32 out
// ---------------------------------------------------------------------------
__global__ __launch_bounds__(256)
void wo_kernel(const short* __restrict__ attnb, const float* __restrict__ wo,
               float* __restrict__ out)
{
  __shared__ short As[64][40], Bs[64][40];
  int lin = blockIdx.x;
  lin = (lin & 7) * 32 + (lin >> 3);
  int m0 = (lin & 3) * 64, n0 = (lin >> 2) * 64;
  int tid = threadIdx.x, w = tid >> 6, l = tid & 63;
  f4_t acc[4];
#pragma unroll
  for (int i = 0; i < 4; i++) acc[i] = zf4();
  int arow = tid >> 2, akc = (tid & 3) * 8;
  int bn = tid & 63,  bk = (tid >> 6) * 8;

  for (int kk = 0; kk < 4096; kk += 32) {
    __syncthreads();
    *(bf8_t*)&As[arow][akc] =
        *(const bf8_t*)(attnb + (m0 + arow) * 4096 + kk + akc);
    {
      bf8_t hv;
#pragma unroll
      for (int j = 0; j < 8; j++) hv[j] = f2bf(wo[(kk + bk + j) * 4096 + n0 + bn]);
      *(bf8_t*)&Bs[bn][bk] = hv;
    }
    __syncthreads();
    bf8_t a = *(const bf8_t*)&As[w * 16 + (l & 15)][(l >> 4) * 8];
#pragma unroll
    for (int nt = 0; nt < 4; ++nt) {
      bf8_t bb_ = *(const bf8_t*)&Bs[nt * 16 + (l & 15)][(l >> 4) * 8];
      acc[nt] = mfma16(a, bb_, acc[nt]);
    }
  }
  int cl = l & 15, gq = l >> 4;
#pragma unroll
  for (int nt = 0; nt < 4; ++nt)
#pragma unroll
    for (int i = 0; i < 4; i++)
      out[(m0 + w * 16 + gq * 4 + i) * 4096 + n0 + nt * 16 + cl] = acc[nt][i];
}

// ---------------------------------------------------------------------------
extern "C" void kernel_launch(void* const* d_in, const int* in_sizes, int n_in,
                              void* d_out, int out_size, void* d_ws, size_t ws_size,
                              hipStream_t stream)
{
  const float* x  = (const float*)d_in[0];
  const float* k  = (const float*)d_in[1];
  const float* v  = (const float*)d_in[2];
  const float* wq = (const float*)d_in[3];
  const float* wk = (const float*)d_in[4];
  const float* wv = (const float*)d_in[5];
  const float* wo = (const float*)d_in[6];
  const float* ck = (const float*)d_in[7];
  const float* cv = (const float*)d_in[8];
  const float* fc = (const float*)d_in[9];
  const float* fs = (const float*)d_in[10];
  const int*   spv = (const int*)d_in[11];
  float* out = (float*)d_out;

  char* p = (char*)d_ws;
  short* qh = (short*)p; p += (size_t)128 * 64 * 128 * 2;   // 2 MB
  short* ql = (short*)p; p += (size_t)128 * 64 * 128 * 2;   // 2 MB
  short* kh = (short*)p; p += (size_t)128 * 16 * 128 * 2;   // 512 KB
  short* kl = (short*)p; p += (size_t)128 * 16 * 128 * 2;   // 512 KB
  short* vb = (short*)p; p += (size_t)128 * 16 * 128 * 2;   // 512 KB
  short* attnb = (short*)p; p += (size_t)256 * 4096 * 2;    // 2 MB
  float* Op = (float*)p; p += (size_t)512 * 64 * 128 * 4;   // 16 MB
  float* mp = (float*)p; p += (size_t)512 * 64 * 4;
  float* lp = (float*)p; p += (size_t)512 * 64 * 4;

  hipLaunchKernelGGL(qkv_kernel, dim3(384), dim3(256), 0, stream,
                     x, k, v, wq, wk, wv, fc, fs, qh, ql, kh, kl, vb);
  hipLaunchKernelGGL(attn_kernel, dim3(512), dim3(256), 0, stream,
                     ck, cv, qh, ql, kh, kl, vb, spv, Op, mp, lp);
  hipLaunchKernelGGL(merge_kernel, dim3(128), dim3(256), 0, stream,
                     Op, mp, lp, attnb);
  hipLaunchKernelGGL(wo_kernel, dim3(256), dim3(256), 0, stream,
                     attnb, wo, out);
}

// Round 2
// 288.635 us; speedup vs baseline: 1.3730x; 1.3730x over previous
//
#include <hip/hip_runtime.h>

typedef __attribute__((ext_vector_type(8))) short bf8_t;   // 8 bf16 (4 VGPRs)
typedef __attribute__((ext_vector_type(4))) short s4_t;    // 4 bf16
typedef __attribute__((ext_vector_type(4))) float f4_t;    // 4 f32

#define DEV static __device__ __forceinline__

DEV short f2bf(float f) {
  union { float f; unsigned u; } x; x.f = f;
  unsigned r = x.u + 0x7FFFu + ((x.u >> 16) & 1u);   // RNE
  return (short)(r >> 16);
}
DEV float bf2f(short h) {
  union { unsigned u; float f; } x; x.u = ((unsigned)(unsigned short)h) << 16;
  return x.f;
}
DEV f4_t mfma16(bf8_t a, bf8_t b, f4_t c) {
  return __builtin_amdgcn_mfma_f32_16x16x32_bf16(a, b, c, 0, 0, 0);
}
DEV f4_t zf4() { f4_t v = {0.f, 0.f, 0.f, 0.f}; return v; }

// split f32x8 -> bf16 hi + bf16 lo
DEV void cvt8(const f4_t& f0, const f4_t& f1, bf8_t& hv, bf8_t& lv) {
#pragma unroll
  for (int i = 0; i < 4; i++) {
    short h = f2bf(f0[i]); hv[i] = h; lv[i] = f2bf(f0[i] - bf2f(h));
  }
#pragma unroll
  for (int i = 0; i < 4; i++) {
    short h = f2bf(f1[i]); hv[4 + i] = h; lv[4 + i] = f2bf(f1[i] - bf2f(h));
  }
}

// ---------------------------------------------------------------------------
// Kernel 1: QKV projection, split-K=4, double-buffered B staging, A direct
// from global (L2-resident). Output: f32 partials part[4][256][6144].
// Grid 1536 = 384 tiles x 4 ksplits, XCD-swizzled, m-tile fastest for L2.
// ---------------------------------------------------------------------------
__global__ __launch_bounds__(256, 4)
void qkv_kernel(const float* __restrict__ x, const float* __restrict__ kin,
                const float* __restrict__ vin, const float* __restrict__ wq,
                const float* __restrict__ wk, const float* __restrict__ wv,
                float* __restrict__ part)
{
  __shared__ short Bh[2][64][40], Bl[2][64][40];   // [buf][n][k] 20 KB

  int bid = blockIdx.x;
  int sw = (bid & 7) * 192 + (bid >> 3);           // XCD-contiguous
  int ks = sw / 384;
  int r  = sw % 384;

  int lin, N, cbase;
  const float* A; const float* W;
  if (r < 256)      { lin = r;       A = x;   W = wq; N = 4096; cbase = 0; }
  else if (r < 320) { lin = r - 256; A = kin; W = wk; N = 1024; cbase = 4096; }
  else              { lin = r - 320; A = vin; W = wv; N = 1024; cbase = 5120; }
  int m0 = (lin & 3) * 64;
  int n0 = (lin >> 2) * 64;
  int k0 = ks * 1024;

  int tid = threadIdx.x, w = tid >> 6, l = tid & 63;
  f4_t acc[4];
#pragma unroll
  for (int i = 0; i < 4; i++) acc[i] = zf4();

  // B staging assignment: lane -> (col bn, k-chunk bk). XOR on chunk breaks
  // the 8-way LDS write conflict (banks = 20*bn + 4*chunk, period-8 in bn).
  int bn = tid & 63;
  int bch = (tid >> 6) ^ ((tid >> 3) & 3);
  int bk = bch * 8;
  const float* wptr = W + n0 + bn;

  // A fragment pointer (direct global; x/k/v are 4 MB -> L2 resident)
  const float* afrag = A + (m0 + w * 16 + (l & 15)) * 4096 + k0 + (l >> 4) * 8;

  // prologue loads (iter 0)
  f4_t a0 = *(const f4_t*)afrag;
  f4_t a1 = *(const f4_t*)(afrag + 4);
  float br[8];
#pragma unroll
  for (int j = 0; j < 8; j++) br[j] = wptr[(size_t)(k0 + bk + j) * N];

  for (int it = 0; it < 32; ++it) {
    int cur = it & 1;
    {   // convert + write B tile
      f4_t f0, f1;
#pragma unroll
      for (int j = 0; j < 4; j++) { f0[j] = br[j]; f1[j] = br[4 + j]; }
      bf8_t hv, lv; cvt8(f0, f1, hv, lv);
      *(bf8_t*)&Bh[cur][bn][bk] = hv;
      *(bf8_t*)&Bl[cur][bn][bk] = lv;
    }
    f4_t a0c = a0, a1c = a1;
    if (it + 1 < 32) {   // prefetch next slice (in flight across barrier+MFMA)
      a0 = *(const f4_t*)(afrag + (it + 1) * 32);
      a1 = *(const f4_t*)(afrag + (it + 1) * 32 + 4);
#pragma unroll
      for (int j = 0; j < 8; j++)
        br[j] = wptr[(size_t)(k0 + (it + 1) * 32 + bk + j) * N];
    }
    __syncthreads();
    bf8_t ah, al; cvt8(a0c, a1c, ah, al);
    __builtin_amdgcn_s_setprio(1);
#pragma unroll
    for (int nt = 0; nt < 4; ++nt) {
      bf8_t bh = *(const bf8_t*)&Bh[cur][nt * 16 + (l & 15)][(l >> 4) * 8];
      bf8_t bl = *(const bf8_t*)&Bl[cur][nt * 16 + (l & 15)][(l >> 4) * 8];
      acc[nt] = mfma16(ah, bh, acc[nt]);
      acc[nt] = mfma16(ah, bl, acc[nt]);
      acc[nt] = mfma16(al, bh, acc[nt]);
    }
    __builtin_amdgcn_s_setprio(0);
  }

  // store f32 partials
  float* po = part + ((size_t)ks * 256 + m0) * 6144 + cbase + n0;
  int cl = l & 15, gq = l >> 4;
#pragma unroll
  for (int nt = 0; nt < 4; ++nt)
#pragma unroll
    for (int i = 0; i < 4; i++)
      po[(w * 16 + gq * 4 + i) * 6144 + nt * 16 + cl] = acc[nt][i];
}

// ---------------------------------------------------------------------------
// Kernel 2: sum 4 partials + RoPE + split into bf16 hi/lo layouts
// ---------------------------------------------------------------------------
__global__ __launch_bounds__(256)
void reduce_rope(const float* __restrict__ part,
                 const float* __restrict__ fcos, const float* __restrict__ fsin,
                 short* __restrict__ qh, short* __restrict__ ql,
                 short* __restrict__ kh, short* __restrict__ kl,
                 short* __restrict__ vb)
{
  int gid = blockIdx.x * 256 + threadIdx.x;    // 768 blocks -> 196608 threads
  int row = gid / 768;
  int c8  = (gid - row * 768) * 8;
  const float* p = part + (size_t)row * 6144 + c8;
  float v[8];
#pragma unroll
  for (int j = 0; j < 8; j++) v[j] = p[j];
#pragma unroll
  for (int ksp = 1; ksp < 4; ksp++) {
    const float* q = p + (size_t)ksp * 256 * 6144;
#pragma unroll
    for (int j = 0; j < 8; j++) v[j] += q[j];
  }
  int s = row & 15, bb = row >> 4;
  if (c8 < 4096) {           // Q: rope + scale + split
    int h = c8 >> 7, d = c8 & 127;
    f4_t c  = *(const f4_t*)(fcos + s * 64 + (d >> 1));
    f4_t sn = *(const f4_t*)(fsin + s * 64 + (d >> 1));
    bf8_t hv, lv;
#pragma unroll
    for (int pr = 0; pr < 4; pr++) {
      float x0 = v[2 * pr], x1 = v[2 * pr + 1];
      float r0 = (x0 * c[pr] - x1 * sn[pr]) * 0.08838834764831845f;
      float r1 = (x0 * sn[pr] + x1 * c[pr]) * 0.08838834764831845f;
      short h0 = f2bf(r0); hv[2 * pr] = h0; lv[2 * pr] = f2bf(r0 - bf2f(h0));
      short h1 = f2bf(r1); hv[2 * pr + 1] = h1; lv[2 * pr + 1] = f2bf(r1 - bf2f(h1));
    }
    int idx = ((bb * 8 + (h >> 2)) * 64 + (h & 3) * 16 + s) * 128 + d;
    *(bf8_t*)(qh + idx) = hv;
    *(bf8_t*)(ql + idx) = lv;
  } else if (c8 < 5120) {    // K: rope + split
    int cc = c8 - 4096; int h = cc >> 7, d = cc & 127;
    f4_t c  = *(const f4_t*)(fcos + s * 64 + (d >> 1));
    f4_t sn = *(const f4_t*)(fsin + s * 64 + (d >> 1));
    bf8_t hv, lv;
#pragma unroll
    for (int pr = 0; pr < 4; pr++) {
      float x0 = v[2 * pr], x1 = v[2 * pr + 1];
      float r0 = x0 * c[pr] - x1 * sn[pr];
      float r1 = x0 * sn[pr] + x1 * c[pr];
      short h0 = f2bf(r0); hv[2 * pr] = h0; lv[2 * pr] = f2bf(r0 - bf2f(h0));
      short h1 = f2bf(r1); hv[2 * pr + 1] = h1; lv[2 * pr + 1] = f2bf(r1 - bf2f(h1));
    }
    int idx = ((bb * 8 + h) * 16 + s) * 128 + d;
    *(bf8_t*)(kh + idx) = hv;
    *(bf8_t*)(kl + idx) = lv;
  } else {                   // V: plain bf16
    int cc = c8 - 5120; int h = cc >> 7, d = cc & 127;
    bf8_t hv;
#pragma unroll
    for (int j = 0; j < 8; j++) hv[j] = f2bf(v[j]);
    int idx = ((bb * 8 + h) * 16 + s) * 128 + d;
    *(bf8_t*)(vb + idx) = hv;
  }
}

// ---------------------------------------------------------------------------
// Kernel 3: flash attention (unchanged structure + setprio around MFMA)
// ---------------------------------------------------------------------------
__global__ __launch_bounds__(256)
void attn_kernel(const float* __restrict__ ck, const float* __restrict__ cv,
                 const short* __restrict__ qhp, const short* __restrict__ qlp,
                 const short* __restrict__ khp, const short* __restrict__ klp,
                 const short* __restrict__ vbp, const int* __restrict__ startp,
                 float* __restrict__ Op, float* __restrict__ mp,
                 float* __restrict__ lp)
{
  __shared__ short Kh[64][136], Kl[64][136];  // [t][d]
  __shared__ short Vt[128][72];               // [d][t]
  __shared__ short Ps[4][16][72];             // per-wave P [qrow][t]

  int bid = blockIdx.x;
  int bg = bid >> 2, sp = bid & 3;
  int b = bg >> 3, g = bg & 7;
  int tid = threadIdx.x, w = tid >> 6, l = tid & 63;
  int start = *startp;

  bf8_t qfh[4], qfl[4];
  {
    int qoff = (bg * 64 + w * 16 + (l & 15)) * 128 + (l >> 4) * 8;
#pragma unroll
    for (int kt = 0; kt < 4; ++kt) {
      qfh[kt] = *(const bf8_t*)(qhp + qoff + kt * 32);
      qfl[kt] = *(const bf8_t*)(qlp + qoff + kt * 32);
    }
  }
  f4_t of[8];
#pragma unroll
  for (int i = 0; i < 8; i++) of[i] = zf4();
  float mrun[4], lrun[4];
#pragma unroll
  for (int i = 0; i < 4; i++) { mrun[i] = -1e30f; lrun[i] = 0.f; }

  int srow = tid >> 2, sdc = (tid & 3) * 32;   // staging: row, d-quarter

  for (int tile = 0; tile < 16; ++tile) {
    int tb = sp * 1024 + tile * 64;
    __syncthreads();
    {   // stage K (hi/lo)
      int t = tb + srow;
      if (t >= start) {
        const short* sh = khp + ((bg * 16) + (t - start)) * 128 + sdc;
        const short* sl = klp + ((bg * 16) + (t - start)) * 128 + sdc;
#pragma unroll
        for (int j = 0; j < 4; j++) {
          *(bf8_t*)&Kh[srow][sdc + j * 8] = *(const bf8_t*)(sh + j * 8);
          *(bf8_t*)&Kl[srow][sdc + j * 8] = *(const bf8_t*)(sl + j * 8);
        }
      } else {
        const float* src = ck + (((size_t)b * 4096 + t) * 8 + g) * 128 + sdc;
#pragma unroll
        for (int j = 0; j < 4; j++) {
          f4_t f0 = *(const f4_t*)(src + j * 8);
          f4_t f1 = *(const f4_t*)(src + j * 8 + 4);
          bf8_t hv, lv; cvt8(f0, f1, hv, lv);
          *(bf8_t*)&Kh[srow][sdc + j * 8] = hv;
          *(bf8_t*)&Kl[srow][sdc + j * 8] = lv;
        }
      }
    }
    {   // stage V transposed
      int t = tb + srow;
      if (t >= start) {
        const short* sv = vbp + ((bg * 16) + (t - start)) * 128 + sdc;
#pragma unroll
        for (int j = 0; j < 4; j++) {
          bf8_t vv = *(const bf8_t*)(sv + j * 8);
#pragma unroll
          for (int i = 0; i < 8; i++) Vt[sdc + j * 8 + i][srow] = vv[i];
        }
      } else {
        const float* src = cv + (((size_t)b * 4096 + t) * 8 + g) * 128 + sdc;
#pragma unroll
        for (int j = 0; j < 8; j++) {
          f4_t f = *(const f4_t*)(src + j * 4);
#pragma unroll
          for (int i = 0; i < 4; i++) Vt[sdc + j * 4 + i][srow] = f2bf(f[i]);
        }
      }
    }
    __syncthreads();

    // QK^T (split: qh*kh + qh*kl + ql*kh)
    f4_t sf[4];
#pragma unroll
    for (int i = 0; i < 4; i++) sf[i] = zf4();
    __builtin_amdgcn_s_setprio(1);
#pragma unroll
    for (int tt = 0; tt < 4; ++tt) {
#pragma unroll
      for (int kt = 0; kt < 4; ++kt) {
        bf8_t kbh = *(const bf8_t*)&Kh[tt * 16 + (l & 15)][kt * 32 + (l >> 4) * 8];
        bf8_t kbl = *(const bf8_t*)&Kl[tt * 16 + (l & 15)][kt * 32 + (l >> 4) * 8];
        sf[tt] = mfma16(qfh[kt], kbh, sf[tt]);
        sf[tt] = mfma16(qfh[kt], kbl, sf[tt]);
        sf[tt] = mfma16(qfl[kt], kbh, sf[tt]);
      }
    }
    __builtin_amdgcn_s_setprio(0);

    // online softmax; C layout: row=(l>>4)*4+i, col=tt*16+(l&15)
    float mt[4];
#pragma unroll
    for (int i = 0; i < 4; i++)
      mt[i] = fmaxf(fmaxf(sf[0][i], sf[1][i]), fmaxf(sf[2][i], sf[3][i]));
#pragma unroll
    for (int st = 1; st < 16; st <<= 1)
#pragma unroll
      for (int i = 0; i < 4; i++) mt[i] = fmaxf(mt[i], __shfl_xor(mt[i], st));
    float sc[4];
#pragma unroll
    for (int i = 0; i < 4; i++) {
      float mn = fmaxf(mrun[i], mt[i]);
      sc[i] = __expf(mrun[i] - mn);
      mrun[i] = mn;
    }
    float rs[4] = {0.f, 0.f, 0.f, 0.f};
#pragma unroll
    for (int tt = 0; tt < 4; ++tt)
#pragma unroll
      for (int i = 0; i < 4; i++) {
        float pexp = __expf(sf[tt][i] - mrun[i]);
        rs[i] += pexp;
        Ps[w][(l >> 4) * 4 + i][tt * 16 + (l & 15)] = f2bf(pexp);
      }
#pragma unroll
    for (int st = 1; st < 16; st <<= 1)
#pragma unroll
      for (int i = 0; i < 4; i++) rs[i] += __shfl_xor(rs[i], st);
#pragma unroll
    for (int i = 0; i < 4; i++) lrun[i] = lrun[i] * sc[i] + rs[i];
#pragma unroll
    for (int dt = 0; dt < 8; ++dt)
#pragma unroll
      for (int i = 0; i < 4; i++) of[dt][i] *= sc[i];

    // PV
    __builtin_amdgcn_s_setprio(1);
#pragma unroll
    for (int kt2 = 0; kt2 < 2; ++kt2) {
      bf8_t pa = *(const bf8_t*)&Ps[w][l & 15][kt2 * 32 + (l >> 4) * 8];
#pragma unroll
      for (int dt = 0; dt < 8; ++dt) {
        bf8_t vf = *(const bf8_t*)&Vt[dt * 16 + (l & 15)][kt2 * 32 + (l >> 4) * 8];
        of[dt] = mfma16(pa, vf, of[dt]);
      }
    }
    __builtin_amdgcn_s_setprio(0);
  }

  // write partials
  size_t obase = ((size_t)(bg * 4 + sp) * 64 + w * 16) * 128;
#pragma unroll
  for (int dt = 0; dt < 8; ++dt)
#pragma unroll
    for (int i = 0; i < 4; i++)
      Op[obase + ((l >> 4) * 4 + i) * 128 + dt * 16 + (l & 15)] = of[dt][i];
  if ((l & 15) == 0) {
    int rbase = (bg * 4 + sp) * 64 + w * 16 + (l >> 4) * 4;
#pragma unroll
    for (int i = 0; i < 4; i++) { mp[rbase + i] = mrun[i]; lp[rbase + i] = lrun[i]; }
  }
}

// ---------------------------------------------------------------------------
// Kernel 4: merge the 4 softmax partials -> bf16 attn-out (256 x 4096)
// ---------------------------------------------------------------------------
__global__ __launch_bounds__(256)
void merge_kernel(const float* __restrict__ Op, const float* __restrict__ mp,
                  const float* __restrict__ lp, short* __restrict__ attnb)
{
  int bg = blockIdx.x;
  int tid = threadIdx.x;
  int row = tid >> 2, dc = (tid & 3) * 32;
  int b = bg >> 3, g = bg & 7;
  int r = row >> 4, s = row & 15;
  float mm[4], ww[4];
  float M = -1e30f;
#pragma unroll
  for (int spp = 0; spp < 4; ++spp) {
    mm[spp] = mp[(bg * 4 + spp) * 64 + row];
    M = fmaxf(M, mm[spp]);
  }
  float denom = 0.f;
#pragma unroll
  for (int spp = 0; spp < 4; ++spp) {
    ww[spp] = __expf(mm[spp] - M);
    denom += lp[(bg * 4 + spp) * 64 + row] * ww[spp];
  }
  float inv = 1.0f / denom;
  int ob = (b * 16 + s) * 4096 + (g * 4 + r) * 128 + dc;
#pragma unroll
  for (int j = 0; j < 8; j++) {
    f4_t a = zf4();
#pragma unroll
    for (int spp = 0; spp < 4; ++spp) {
      f4_t o = *(const f4_t*)(Op + ((size_t)(bg * 4 + spp) * 64 + row) * 128 + dc + j * 4);
#pragma unroll
      for (int i = 0; i < 4; i++) a[i] += ww[spp] * o[i];
    }
    s4_t o4;
#pragma unroll
    for (int i = 0; i < 4; i++) o4[i] = f2bf(a[i] * inv);
    *(s4_t*)(attnb + ob + j * 4) = o4;
  }
}

// ---------------------------------------------------------------------------
// Kernel 5: output projection, split-K=4, double-buffered, A direct from L2
// ---------------------------------------------------------------------------
__global__ __launch_bounds__(256, 4)
void wo_kernel(const short* __restrict__ attnb, const float* __restrict__ wo,
               float* __restrict__ wpart)
{
  __shared__ short Bs[2][64][40];   // 10 KB

  int bid = blockIdx.x;                       // 1024
  int sw = (bid & 7) * 128 + (bid >> 3);
  int ks = sw >> 8, r = sw & 255;
  int m0 = (r & 3) * 64, n0 = (r >> 2) * 64, k0 = ks * 1024;

  int tid = threadIdx.x, w = tid >> 6, l = tid & 63;
  f4_t acc[4];
#pragma unroll
  for (int i = 0; i < 4; i++) acc[i] = zf4();

  int bn = tid & 63;
  int bch = (tid >> 6) ^ ((tid >> 3) & 3);
  int bk = bch * 8;
  const float* wptr = wo + n0 + bn;
  const short* afrag = attnb + (m0 + w * 16 + (l & 15)) * 4096 + k0 + (l >> 4) * 8;

  bf8_t areg = *(const bf8_t*)afrag;
  float br[8];
#pragma unroll
  for (int j = 0; j < 8; j++) br[j] = wptr[(size_t)(k0 + bk + j) * 4096];

  for (int it = 0; it < 32; ++it) {
    int cur = it & 1;
    {
      bf8_t hv;
#pragma unroll
      for (int j = 0; j < 8; j++) hv[j] = f2bf(br[j]);
      *(bf8_t*)&Bs[cur][bn][bk] = hv;
    }
    bf8_t ac = areg;
    if (it + 1 < 32) {
      areg = *(const bf8_t*)(afrag + (it + 1) * 32);
#pragma unroll
      for (int j = 0; j < 8; j++)
        br[j] = wptr[(size_t)(k0 + (it + 1) * 32 + bk + j) * 4096];
    }
    __syncthreads();
    __builtin_amdgcn_s_setprio(1);
#pragma unroll
    for (int nt = 0; nt < 4; ++nt) {
      bf8_t bb_ = *(const bf8_t*)&Bs[cur][nt * 16 + (l & 15)][(l >> 4) * 8];
      acc[nt] = mfma16(ac, bb_, acc[nt]);
    }
    __builtin_amdgcn_s_setprio(0);
  }

  float* po = wpart + ((size_t)ks * 256 + m0) * 4096 + n0;
  int cl = l & 15, gq = l >> 4;
#pragma unroll
  for (int nt = 0; nt < 4; ++nt)
#pragma unroll
    for (int i = 0; i < 4; i++)
      po[(w * 16 + gq * 4 + i) * 4096 + nt * 16 + cl] = acc[nt][i];
}

// ---------------------------------------------------------------------------
// Kernel 6: sum 4 wo partials -> f32 out
// ---------------------------------------------------------------------------
__global__ __launch_bounds__(256)
void reduce_out(const float* __restrict__ wpart, float* __restrict__ out)
{
  int gid = blockIdx.x * 256 + threadIdx.x;   // 1024 blocks, 4 floats each
  size_t idx4 = (size_t)gid * 4;
  f4_t s = *(const f4_t*)(wpart + idx4);
#pragma unroll
  for (int ksp = 1; ksp < 4; ksp++) {
    f4_t t = *(const f4_t*)(wpart + (size_t)ksp * 1048576 + idx4);
#pragma unroll
    for (int i = 0; i < 4; i++) s[i] += t[i];
  }
  *(f4_t*)(out + idx4) = s;
}

// ---------------------------------------------------------------------------
extern "C" void kernel_launch(void* const* d_in, const int* in_sizes, int n_in,
                              void* d_out, int out_size, void* d_ws, size_t ws_size,
                              hipStream_t stream)
{
  const float* x  = (const float*)d_in[0];
  const float* k  = (const float*)d_in[1];
  const float* v  = (const float*)d_in[2];
  const float* wq = (const float*)d_in[3];
  const float* wk = (const float*)d_in[4];
  const float* wv = (const float*)d_in[5];
  const float* wo = (const float*)d_in[6];
  const float* ck = (const float*)d_in[7];
  const float* cv = (const float*)d_in[8];
  const float* fc = (const float*)d_in[9];
  const float* fs = (const float*)d_in[10];
  const int*   spv = (const int*)d_in[11];
  float* out = (float*)d_out;

  // Workspace: S region (25.2 MB) is time-shared by three strictly
  // sequential producers/consumers: qkv partials -> Op -> wo partials.
  char* p = (char*)d_ws;
  float* S = (float*)p; p += (size_t)4 * 256 * 6144 * 4;      // 25.17 MB
  float* qpart = S;
  float* Oppp  = S;
  float* wpart = S;
  short* qh = (short*)p; p += (size_t)128 * 64 * 128 * 2;     // 2 MB
  short* ql = (short*)p; p += (size_t)128 * 64 * 128 * 2;     // 2 MB
  short* kh = (short*)p; p += (size_t)128 * 16 * 128 * 2;     // 512 KB
  short* kl = (short*)p; p += (size_t)128 * 16 * 128 * 2;     // 512 KB
  short* vb = (short*)p; p += (size_t)128 * 16 * 128 * 2;     // 512 KB
  short* attnb = (short*)p; p += (size_t)256 * 4096 * 2;      // 2 MB
  float* mp = (float*)p; p += (size_t)512 * 64 * 4;
  float* lp = (float*)p; p += (size_t)512 * 64 * 4;

  hipLaunchKernelGGL(qkv_kernel, dim3(1536), dim3(256), 0, stream,
                     x, k, v, wq, wk, wv, qpart);
  hipLaunchKernelGGL(reduce_rope, dim3(768), dim3(256), 0, stream,
                     qpart, fc, fs, qh, ql, kh, kl, vb);
  hipLaunchKernelGGL(attn_kernel, dim3(512), dim3(256), 0, stream,
                     ck, cv, qh, ql, kh, kl, vb, spv, Oppp, mp, lp);
  hipLaunchKernelGGL(merge_kernel, dim3(128), dim3(256), 0, stream,
                     Oppp, mp, lp, attnb);
  hipLaunchKernelGGL(wo_kernel, dim3(1024), dim3(256), 0, stream,
                     attnb, wo, wpart);
  hipLaunchKernelGGL(reduce_out, dim3(1024), dim3(256), 0, stream,
                     wpart, out);
}